// Round 12
// baseline (623.015 us; speedup 1.0000x reference)
//
#include <hip/hip_runtime.h>

// ---------------- types / helpers ----------------
typedef __bf16 bf16x8 __attribute__((ext_vector_type(8)));
typedef float  f32x4  __attribute__((ext_vector_type(4)));

__device__ __forceinline__ f32x4 MFMA(bf16x8 a, bf16x8 b, f32x4 c) {
    return __builtin_amdgcn_mfma_f32_16x16x32_bf16(a, b, c, 0, 0, 0);
}

__device__ __forceinline__ unsigned short f2bfu(float f) {
    unsigned int u = __builtin_bit_cast(unsigned int, f);
    u += 0x7FFFu + ((u >> 16) & 1u);
    return (unsigned short)(u >> 16);
}
__device__ __forceinline__ float bf2f(unsigned short s) {
    unsigned int u = ((unsigned int)s) << 16;
    return __builtin_bit_cast(float, u);
}
__device__ __forceinline__ float sigm(float x) { return 1.f / (1.f + __expf(-x)); }
__device__ __forceinline__ float tanh_f(float x) { return 1.f - 2.f / (__expf(2.f * x) + 1.f); }
// concrete dropout: z = sigmoid((plog + log u - log(1-u))/0.1); out = x*(1-z)/(1-p)
__device__ __forceinline__ float cdrop(float x, float u, float plog, float scale) {
    float t = (plog + __logf(u) - __logf(1.f - u)) * 10.f;
    float z = 1.f / (1.f + __expf(-t));
    return x * (1.f - z) * scale;
}

// ---------------- small kernels ----------------
__global__ void k_zero(float* acc) {
    if (threadIdx.x < 4) acc[threadIdx.x] = 0.f;
}

// Convert 5 weight matrices fp32 -> bf16 in MFMA-FRAGMENT order; accumulate sum(W*W).
// frag[t][kk][lane][8]: lane = qd*16+ln holds W[t*16+ln][kk*32+qd*8 .. +7].
// A wave's B-fragment load is ONE contiguous 1 KB global_load.
__global__ void k_convert(const float* __restrict__ Win, const float* __restrict__ Wih,
                          const float* __restrict__ Whh, const float* __restrict__ Wfc1,
                          const float* __restrict__ Wfc2,
                          unsigned short* __restrict__ WinP, unsigned short* __restrict__ WihP,
                          unsigned short* __restrict__ WhhP, unsigned short* __restrict__ Wfc1P,
                          unsigned short* __restrict__ Wfc2b, float* __restrict__ acc) {
    __shared__ float s3[3];
    int tid = threadIdx.x;
    if (tid < 3) s3[tid] = 0.f;
    __syncthreads();
    int f = blockIdx.x * 256 + tid;   // fragment id, total 72576
    float sq = 0.f; int mi = -1;
    if (f < 72576) {
        const float* src; unsigned short* dst;
        int row, wo, kreal, scols, didx;
        if (f < 1920) {                              // W_in [240][48->64], 128 frags/t
            int t = f >> 7, r = f & 127;
            int kk = r >> 6, qd = (r >> 4) & 3, ln = r & 15;
            row = t * 16 + ln; wo = kk * 32 + qd * 8;
            kreal = 48; scols = 48; src = Win; dst = WinP; didx = f * 8;
            if (wo < 48) mi = 0;
        } else if (f < 24960) {                      // W_ih [720][240->256], 512 frags/t'
            int i = f - 1920;
            int tp = i >> 9, r = i & 511;
            int kk = r >> 6, qd = (r >> 4) & 3, ln = r & 15;
            row = (tp / 15) * 240 + (tp % 15) * 16 + ln; wo = kk * 32 + qd * 8;
            kreal = 240; scols = 240; src = Wih; dst = WihP; didx = i * 8;
        } else if (f < 48000) {                      // W_hh
            int i = f - 24960;
            int tp = i >> 9, r = i & 511;
            int kk = r >> 6, qd = (r >> 4) & 3, ln = r & 15;
            row = (tp / 15) * 240 + (tp % 15) * 16 + ln; wo = kk * 32 + qd * 8;
            kreal = 240; scols = 240; src = Whh; dst = WhhP; didx = i * 8;
        } else if (f < 64384) {                      // W_fc1 [512][240->256]
            int i = f - 48000;
            int t = i >> 9, r = i & 511;
            int kk = r >> 6, qd = (r >> 4) & 3, ln = r & 15;
            row = t * 16 + ln; wo = kk * 32 + qd * 8;
            kreal = 240; scols = 240; src = Wfc1; dst = Wfc1P; didx = i * 8;
            if (wo < 240) mi = 1;
        } else {                                     // W_fc2 [128][512], no pad
            int i = f - 64384;
            int t = i >> 10, r = i & 1023;
            int kk = r >> 6, qd = (r >> 4) & 3, ln = r & 15;
            row = t * 16 + ln; wo = kk * 32 + qd * 8;
            kreal = 512; scols = 512; src = Wfc2; dst = Wfc2b; didx = i * 8;
            mi = 2;
        }
        ushort4 o0 = {0, 0, 0, 0}, o1 = {0, 0, 0, 0};
        if (wo < kreal) {
            float4 v0 = *(const float4*)(src + (size_t)row * scols + wo);
            float4 v1 = *(const float4*)(src + (size_t)row * scols + wo + 4);
            o0.x = f2bfu(v0.x); o0.y = f2bfu(v0.y); o0.z = f2bfu(v0.z); o0.w = f2bfu(v0.w);
            o1.x = f2bfu(v1.x); o1.y = f2bfu(v1.y); o1.z = f2bfu(v1.z); o1.w = f2bfu(v1.w);
            sq = v0.x * v0.x + v0.y * v0.y + v0.z * v0.z + v0.w * v0.w
               + v1.x * v1.x + v1.y * v1.y + v1.z * v1.z + v1.w * v1.w;
        }
        *(ushort4*)(dst + didx) = o0;
        *(ushort4*)(dst + didx + 4) = o1;
    }
    if (mi >= 0) atomicAdd(&s3[mi], sq);
    __syncthreads();
    if (tid < 3) atomicAdd(&acc[tid], s3[tid]);
}

// x_filt_prev_mean[b][m] = mean_s x_ens[s,b,m]
__global__ void k_colmean(const float* __restrict__ x_ens, float* __restrict__ xfpm) {
    int t = blockIdx.x * 256 + threadIdx.x;   // < 32768
    float s = 0.f;
    for (int ss = 0; ss < 32; ++ss) s += x_ens[ss * 32768 + t];
    xfpm[t] = s * (1.f / 32.f);
}

// per-b: x_pred_mean = xfpm @ F^T, innov = y_t - x_pred_mean @ H^T, feat[48]
__global__ void k_feat(const float* __restrict__ xfpm, const float* __restrict__ F_mat,
                       const float* __restrict__ H_mat, const float* __restrict__ y_t,
                       const float* __restrict__ y_prev, const float* __restrict__ xppm,
                       const float* __restrict__ xpdm, float* __restrict__ feat,
                       float* __restrict__ innov) {
    int b = blockIdx.x * 256 + threadIdx.x;
    if (b >= 2048) return;
    float xm[16];
    #pragma unroll
    for (int m = 0; m < 16; ++m) xm[m] = xfpm[b * 16 + m];
    float xpm[16];
    #pragma unroll
    for (int k = 0; k < 16; ++k) {
        float a = 0.f;
        #pragma unroll
        for (int m = 0; m < 16; ++m) a += xm[m] * F_mat[k * 16 + m];
        xpm[k] = a;
    }
    #pragma unroll
    for (int n = 0; n < 8; ++n) {
        float a = 0.f;
        #pragma unroll
        for (int k = 0; k < 16; ++k) a += xpm[k] * H_mat[n * 16 + k];
        float inn = y_t[b * 8 + n] - a;
        innov[b * 8 + n] = inn;
        feat[b * 48 + 16 + n] = inn;
        feat[b * 48 + 40 + n] = y_t[b * 8 + n] - y_prev[b * 8 + n];
    }
    #pragma unroll
    for (int m = 0; m < 16; ++m) {
        feat[b * 48 + m]      = xm[m] - xpdm[b * 16 + m];
        feat[b * 48 + 24 + m] = xm[m] - xppm[b * 16 + m];
    }
}

// ---------------- fully fused DNN + Kalman-update kernel (16 rows/block, 256 thr) ----------------
// Occupancy plan (fix for Rd9's latency-bound 44%): shrink block 512->256 thr, 32->16 rows.
// LDS 59.4K -> 30.2K => 5 blocks/CU = 20 waves/CU = 5 waves/SIMD (reg cap 512/5=102;
// structure compiles ~60 VGPR + 24 AGPR = 84, fits). 4096 blocks at many different phase
// positions de-correlate the per-kk L2 weight-load stalls that dominated Rd9 (no pipe >13%).
// Per-element math identical to Rd9 => bit-identical output.
// LDS layout (bytes), total 30208:
//   [    0, 2304) sAin [16][72]    (aliased later by sA5)
//   [ 2304,10752) sA1  [16][264]   (aliased later by sA5)
//   [10752,19200) sA2  [16][264]   (head aliased later by sA5)
//   [19200,27648) sHd  [16][264]
//   [    0,16640) sA5  [16][520]   (phase 3+ only; sAin/sA1/sA2 dead by then)
//   [27648,28160) sInn [128]f32  [28160,29184) sF [256]f32  [29184,30208) sOut [16][16]f32
__global__ __launch_bounds__(256, 5) void k_fused(
    const float* __restrict__ feat, const float* __restrict__ u_in_g,
    const float* __restrict__ h_ens, const float* __restrict__ u_fc1_g,
    const float* __restrict__ u_fc2_g,
    const unsigned short* __restrict__ WinP, const unsigned short* __restrict__ WihP,
    const unsigned short* __restrict__ WhhP, const unsigned short* __restrict__ Wfc1P,
    const unsigned short* __restrict__ Wfc2b,
    const float* __restrict__ b_in, const float* __restrict__ b_ih,
    const float* __restrict__ b_hh, const float* __restrict__ b_fc1,
    const float* __restrict__ b_fc2,
    const float* __restrict__ p_in_l, const float* __restrict__ p_fc1_l,
    const float* __restrict__ p_fc2_l,
    const float* __restrict__ innov_ws, const float* __restrict__ x_ens,
    const float* __restrict__ F_mat, float* __restrict__ out) {

    __shared__ __align__(16) char smem[30208];
    unsigned short* sAin = (unsigned short*)smem;
    unsigned short* sA1  = (unsigned short*)(smem + 2304);
    unsigned short* sA2  = (unsigned short*)(smem + 10752);
    unsigned short* sHd  = (unsigned short*)(smem + 19200);
    unsigned short* sA5  = (unsigned short*)smem;
    float* sInn = (float*)(smem + 27648);
    float* sF   = (float*)(smem + 28160);
    float* sOut = (float*)(smem + 29184);

    int tid = threadIdx.x;
    int lane = tid & 63, wave = tid >> 6;   // 4 waves
    int blk = blockIdx.x;
    int r0 = blk * 16;             // flattened ensemble row (s*2048 + b)
    int b0 = (blk & 127) * 16;     // batch row (feat/innov index)
    float plog_in = p_in_l[0];  float sc_in = 1.f / (1.f - sigm(plog_in));
    float plog_f1 = p_fc1_l[0]; float sc_f1 = 1.f / (1.f - sigm(plog_f1));
    float plog_f2 = p_fc2_l[0]; float sc_f2 = 1.f / (1.f - sigm(plog_f2));

    // ---- P0: stage A_in (cdrop), h_ens->bf16, innov, F; zero K-pads ----
    if (tid < 192) {
        int row = tid / 12, k = (tid % 12) * 4;
        float4 f = *(const float4*)(feat + (b0 + row) * 48 + k);
        float4 u = *(const float4*)(u_in_g + (size_t)(r0 + row) * 48 + k);
        ushort4 o;
        o.x = f2bfu(cdrop(f.x, u.x, plog_in, sc_in));
        o.y = f2bfu(cdrop(f.y, u.y, plog_in, sc_in));
        o.z = f2bfu(cdrop(f.z, u.z, plog_in, sc_in));
        o.w = f2bfu(cdrop(f.w, u.w, plog_in, sc_in));
        *(ushort4*)(sAin + row * 72 + k) = o;
    }
    if (tid < 64) {   // zero pad A_in k in [48,64): 16 rows x 4
        int row = tid / 4, k = 48 + (tid % 4) * 4;
        ushort4 z4 = {0, 0, 0, 0};
        *(ushort4*)(sAin + row * 72 + k) = z4;
    }
    for (int c = tid; c < 960; c += 256) {
        int row = c / 60, k = (c % 60) * 4;
        float4 h = *(const float4*)(h_ens + (size_t)(r0 + row) * 240 + k);
        ushort4 o;
        o.x = f2bfu(h.x); o.y = f2bfu(h.y); o.z = f2bfu(h.z); o.w = f2bfu(h.w);
        *(ushort4*)(sA2 + row * 264 + k) = o;
    }
    if (tid < 96) {   // zero pads k in [240,264) for sA1, sA2, sHd: 16 rows x 6
        int row = tid / 6, k = 240 + (tid % 6) * 4;
        ushort4 z4 = {0, 0, 0, 0};
        *(ushort4*)(sA2 + row * 264 + k) = z4;
        *(ushort4*)(sA1 + row * 264 + k) = z4;
        *(ushort4*)(sHd + row * 264 + k) = z4;
    }
    if (tid < 32) *(float4*)(sInn + tid * 4) = *(const float4*)(innov_ws + b0 * 8 + tid * 4);
    if (tid >= 32 && tid < 96) {
        int q = tid - 32;
        *(float4*)(sF + q * 4) = *(const float4*)(F_mat + q * 4);
    }
    __syncthreads();

    int ln = lane & 15, qd = lane >> 4;

    // ---- P1: x1 = relu(A_in @ W_in^T + b_in) -> sA1 (fragment-ordered WinP) ----
    for (int t = wave; t < 15; t += 4) {
        int col = t * 16 + ln;
        float bias = b_in[col];
        f32x4 a0 = {0.f, 0.f, 0.f, 0.f};
        #pragma unroll
        for (int kk = 0; kk < 2; ++kk) {
            bf16x8 b = *(const bf16x8*)(WinP + ((t * 2 + kk) * 64 + lane) * 8);
            bf16x8 x0 = *(const bf16x8*)(sAin + ln * 72 + kk * 32 + qd * 8);
            a0 = MFMA(x0, b, a0);
        }
        #pragma unroll
        for (int i = 0; i < 4; ++i) {
            int row = qd * 4 + i;
            float v0 = a0[i] + bias;
            sA1[row * 264 + col] = f2bfu(v0 > 0.f ? v0 : 0.f);
        }
    }
    __syncthreads();

    // ---- P2: GRU over 15 tiles; 6 accumulators (24 AGPR); u_fc1 prefetched ----
    // Gate g base offset in fragment layout: g * 61440 ushorts (15 t x 512 frags x 8).
    for (int t = wave; t < 15; t += 4) {
        int j = t * 16 + ln;
        float upf[4];
        #pragma unroll
        for (int i = 0; i < 4; ++i) {
            int row = qd * 4 + i;
            upf[i] = u_fc1_g[(size_t)(r0 + row) * 240 + j];
        }
        float bir_b = b_ih[j], biz_b = b_ih[240 + j], bin_b = b_ih[480 + j];
        float bhr_b = b_hh[j], bhz_b = b_hh[240 + j], bhn_b = b_hh[480 + j];
        f32x4 air = {0,0,0,0}, aiz = {0,0,0,0}, ain = {0,0,0,0};
        f32x4 ahr = {0,0,0,0}, ahz = {0,0,0,0}, ahn = {0,0,0,0};
        #pragma unroll
        for (int kk = 0; kk < 8; ++kk) {
            int wb = ((t * 8 + kk) * 64 + lane) * 8;
            bf16x8 bir = *(const bf16x8*)(WihP + wb);
            bf16x8 biz = *(const bf16x8*)(WihP + 61440 + wb);
            bf16x8 bin_ = *(const bf16x8*)(WihP + 122880 + wb);
            bf16x8 bhr = *(const bf16x8*)(WhhP + wb);
            bf16x8 bhz = *(const bf16x8*)(WhhP + 61440 + wb);
            bf16x8 bhn = *(const bf16x8*)(WhhP + 122880 + wb);
            int ao = ln * 264 + kk * 32 + qd * 8;
            bf16x8 a1f = *(const bf16x8*)(sA1 + ao);
            bf16x8 a2f = *(const bf16x8*)(sA2 + ao);
            air = MFMA(a1f, bir, air);
            aiz = MFMA(a1f, biz, aiz);
            ain = MFMA(a1f, bin_, ain);
            ahr = MFMA(a2f, bhr, ahr);
            ahz = MFMA(a2f, bhz, ahz);
            ahn = MFMA(a2f, bhn, ahn);
        }
        #pragma unroll
        for (int i = 0; i < 4; ++i) {
            int row = qd * 4 + i;
            float rg = sigm(air[i] + bir_b + ahr[i] + bhr_b);
            float zg = sigm(aiz[i] + biz_b + ahz[i] + bhz_b);
            float ng = tanh_f(ain[i] + bin_b + rg * (ahn[i] + bhn_b));
            float hp = bf2f(sA2[row * 264 + j]);
            float hn2 = (1.f - zg) * ng + zg * hp;
            sHd[row * 264 + j] = f2bfu(cdrop(hn2, upf[i], plog_f1, sc_f1));
        }
    }
    __syncthreads();

    // ---- P3: x2 = relu(hd @ W_fc1^T + b); cdrop(u_fc2) -> sA5 (aliases dead bufs) ----
    for (int t = wave; t < 32; t += 4) {
        int col = t * 16 + ln;
        float u0[4];
        #pragma unroll
        for (int i = 0; i < 4; ++i)
            u0[i] = u_fc2_g[(size_t)(r0 + qd * 4 + i) * 512 + col];
        float bias = b_fc1[col];
        f32x4 a0 = {0.f, 0.f, 0.f, 0.f};
        #pragma unroll
        for (int kk = 0; kk < 8; ++kk) {
            bf16x8 b = *(const bf16x8*)(Wfc1P + ((t * 8 + kk) * 64 + lane) * 8);
            bf16x8 x0 = *(const bf16x8*)(sHd + ln * 264 + kk * 32 + qd * 8);
            a0 = MFMA(x0, b, a0);
        }
        #pragma unroll
        for (int i = 0; i < 4; ++i) {
            int row = qd * 4 + i;
            float v0 = a0[i] + bias; v0 = v0 > 0.f ? v0 : 0.f;
            sA5[row * 520 + col] = f2bfu(cdrop(v0, u0[i], plog_f2, sc_f2));
        }
    }
    __syncthreads();

    // ---- P4: K_vec = A5 @ W_fc2^T + b_fc2; K@innov -> sOut ----
    for (int t = wave; t < 8; t += 4) {
        int j = t * 16 + ln;
        float bias = b_fc2[j];
        int n = lane & 7;
        int m = 2 * t + ((lane >> 3) & 1);
        f32x4 a0 = {0.f, 0.f, 0.f, 0.f};
        #pragma unroll
        for (int kk = 0; kk < 16; ++kk) {
            bf16x8 b = *(const bf16x8*)(Wfc2b + ((t * 16 + kk) * 64 + lane) * 8);
            bf16x8 x0 = *(const bf16x8*)(sA5 + ln * 520 + kk * 32 + qd * 8);
            a0 = MFMA(x0, b, a0);
        }
        #pragma unroll
        for (int i = 0; i < 4; ++i) {
            int row = qd * 4 + i;
            float kv = a0[i] + bias;
            float pr = kv * sInn[row * 8 + n];
            pr += __shfl_xor(pr, 1);
            pr += __shfl_xor(pr, 2);
            pr += __shfl_xor(pr, 4);
            if (n == 0) sOut[row * 16 + m] = pr;
        }
    }
    __syncthreads();

    // ---- P5: out = x_ens @ F^T + K@innov, coalesced single write ----
    if (tid < 16) {
        int row = tid;
        float x[16];
        #pragma unroll
        for (int q = 0; q < 4; ++q)
            *(float4*)(x + q * 4) = *(const float4*)(x_ens + (size_t)(r0 + row) * 16 + q * 4);
        #pragma unroll
        for (int mq = 0; mq < 4; ++mq) {
            float4 o;
            float* op = (float*)&o;
            #pragma unroll
            for (int mm = 0; mm < 4; ++mm) {
                int m = mq * 4 + mm;
                float a = 0.f;
                #pragma unroll
                for (int k2 = 0; k2 < 16; ++k2) a += sF[m * 16 + k2] * x[k2];
                op[mm] = a + sOut[row * 16 + m];
            }
            *(float4*)(out + (size_t)(r0 + row) * 16 + mq * 4) = o;
        }
    }
}

// ---------------- regularizer ----------------
__global__ void k_reg(const float* __restrict__ acc, const float* __restrict__ pin,
                      const float* __restrict__ pfc1, const float* __restrict__ pfc2,
                      float* __restrict__ out) {
    float fan[3] = {48.f, 240.f, 512.f};
    float pl[3] = {pin[0], pfc1[0], pfc2[0]};
    float reg = 0.f;
    for (int i = 0; i < 3; ++i) {
        float p = 1.f / (1.f + expf(-pl[i]));
        reg += acc[i] / (1.f - p) + fan[i] * (p * logf(p) + (1.f - p) * logf(1.f - p));
    }
    if (threadIdx.x < 32) out[1048576 + threadIdx.x] = reg;
}

// ---------------- launch ----------------
extern "C" void kernel_launch(void* const* d_in, const int* in_sizes, int n_in,
                              void* d_out, int out_size, void* d_ws, size_t ws_size,
                              hipStream_t stream) {
    const float* y_t    = (const float*)d_in[0];
    const float* x_ens  = (const float*)d_in[1];
    const float* xppm   = (const float*)d_in[2];
    const float* xpdm   = (const float*)d_in[3];
    const float* y_prev = (const float*)d_in[4];
    const float* h_ens  = (const float*)d_in[5];
    const float* F_mat  = (const float*)d_in[6];
    const float* H_mat  = (const float*)d_in[7];
    const float* W_in   = (const float*)d_in[8];
    const float* b_in   = (const float*)d_in[9];
    const float* W_ih   = (const float*)d_in[10];
    const float* b_ih   = (const float*)d_in[11];
    const float* W_hh   = (const float*)d_in[12];
    const float* b_hh   = (const float*)d_in[13];
    const float* W_fc1  = (const float*)d_in[14];
    const float* b_fc1  = (const float*)d_in[15];
    const float* W_fc2  = (const float*)d_in[16];
    const float* b_fc2  = (const float*)d_in[17];
    const float* p_in   = (const float*)d_in[18];
    const float* p_fc1  = (const float*)d_in[19];
    const float* p_fc2  = (const float*)d_in[20];
    const float* u_in   = (const float*)d_in[21];
    const float* u_fc1  = (const float*)d_in[22];
    const float* u_fc2  = (const float*)d_in[23];

    char* ws = (char*)d_ws;
    float* acc            = (float*)(ws + 0);
    unsigned short* WinP  = (unsigned short*)(ws + 64);
    unsigned short* WihP  = (unsigned short*)(ws + 30784);
    unsigned short* WhhP  = (unsigned short*)(ws + 399424);
    unsigned short* Wfc1P = (unsigned short*)(ws + 768064);
    unsigned short* Wfc2b = (unsigned short*)(ws + 1030208);
    float* xfpm           = (float*)(ws + 1161280);
    float* feat           = (float*)(ws + 1292352);
    float* innov          = (float*)(ws + 1685568);
    float* out = (float*)d_out;

    k_zero<<<1, 64, 0, stream>>>(acc);
    k_convert<<<284, 256, 0, stream>>>(W_in, W_ih, W_hh, W_fc1, W_fc2,
                                       WinP, WihP, WhhP, Wfc1P, Wfc2b, acc);
    k_colmean<<<128, 256, 0, stream>>>(x_ens, xfpm);
    k_feat<<<8, 256, 0, stream>>>(xfpm, F_mat, H_mat, y_t, y_prev, xppm, xpdm, feat, innov);
    k_fused<<<4096, 256, 0, stream>>>(feat, u_in, h_ens, u_fc1, u_fc2,
                                      WinP, WihP, WhhP, Wfc1P, Wfc2b,
                                      b_in, b_ih, b_hh, b_fc1, b_fc2,
                                      p_in, p_fc1, p_fc2, innov, x_ens, F_mat, out);
    k_reg<<<1, 64, 0, stream>>>(acc, p_in, p_fc1, p_fc2, out);
}

// Round 13
// 594.903 us; speedup vs baseline: 1.0473x; 1.0473x over previous
//
#include <hip/hip_runtime.h>

// ---------------- types / helpers ----------------
typedef __bf16 bf16x8 __attribute__((ext_vector_type(8)));
typedef float  f32x4  __attribute__((ext_vector_type(4)));

__device__ __forceinline__ f32x4 MFMA(bf16x8 a, bf16x8 b, f32x4 c) {
    return __builtin_amdgcn_mfma_f32_16x16x32_bf16(a, b, c, 0, 0, 0);
}

__device__ __forceinline__ unsigned short f2bfu(float f) {
    unsigned int u = __builtin_bit_cast(unsigned int, f);
    u += 0x7FFFu + ((u >> 16) & 1u);
    return (unsigned short)(u >> 16);
}
__device__ __forceinline__ float bf2f(unsigned short s) {
    unsigned int u = ((unsigned int)s) << 16;
    return __builtin_bit_cast(float, u);
}
__device__ __forceinline__ float sigm(float x) { return 1.f / (1.f + __expf(-x)); }
__device__ __forceinline__ float tanh_f(float x) { return 1.f - 2.f / (__expf(2.f * x) + 1.f); }
// concrete dropout: z = sigmoid((plog + log u - log(1-u))/0.1); out = x*(1-z)/(1-p)
__device__ __forceinline__ float cdrop(float x, float u, float plog, float scale) {
    float t = (plog + __logf(u) - __logf(1.f - u)) * 10.f;
    float z = 1.f / (1.f + __expf(-t));
    return x * (1.f - z) * scale;
}

// ---------------- small kernels ----------------
__global__ void k_zero(float* acc) {
    if (threadIdx.x < 4) acc[threadIdx.x] = 0.f;
}

// Convert 5 weight matrices fp32 -> bf16 in MFMA-FRAGMENT order; accumulate sum(W*W).
// frag[t][kk][lane][8]: lane = qd*16+ln holds W[t*16+ln][kk*32+qd*8 .. +7].
// A wave's B-fragment load is ONE contiguous 1 KB global_load.
__global__ void k_convert(const float* __restrict__ Win, const float* __restrict__ Wih,
                          const float* __restrict__ Whh, const float* __restrict__ Wfc1,
                          const float* __restrict__ Wfc2,
                          unsigned short* __restrict__ WinP, unsigned short* __restrict__ WihP,
                          unsigned short* __restrict__ WhhP, unsigned short* __restrict__ Wfc1P,
                          unsigned short* __restrict__ Wfc2b, float* __restrict__ acc) {
    __shared__ float s3[3];
    int tid = threadIdx.x;
    if (tid < 3) s3[tid] = 0.f;
    __syncthreads();
    int f = blockIdx.x * 256 + tid;   // fragment id, total 72576
    float sq = 0.f; int mi = -1;
    if (f < 72576) {
        const float* src; unsigned short* dst;
        int row, wo, kreal, scols, didx;
        if (f < 1920) {                              // W_in [240][48->64], 128 frags/t
            int t = f >> 7, r = f & 127;
            int kk = r >> 6, qd = (r >> 4) & 3, ln = r & 15;
            row = t * 16 + ln; wo = kk * 32 + qd * 8;
            kreal = 48; scols = 48; src = Win; dst = WinP; didx = f * 8;
            if (wo < 48) mi = 0;
        } else if (f < 24960) {                      // W_ih [720][240->256], 512 frags/t'
            int i = f - 1920;
            int tp = i >> 9, r = i & 511;
            int kk = r >> 6, qd = (r >> 4) & 3, ln = r & 15;
            row = (tp / 15) * 240 + (tp % 15) * 16 + ln; wo = kk * 32 + qd * 8;
            kreal = 240; scols = 240; src = Wih; dst = WihP; didx = i * 8;
        } else if (f < 48000) {                      // W_hh
            int i = f - 24960;
            int tp = i >> 9, r = i & 511;
            int kk = r >> 6, qd = (r >> 4) & 3, ln = r & 15;
            row = (tp / 15) * 240 + (tp % 15) * 16 + ln; wo = kk * 32 + qd * 8;
            kreal = 240; scols = 240; src = Whh; dst = WhhP; didx = i * 8;
        } else if (f < 64384) {                      // W_fc1 [512][240->256]
            int i = f - 48000;
            int t = i >> 9, r = i & 511;
            int kk = r >> 6, qd = (r >> 4) & 3, ln = r & 15;
            row = t * 16 + ln; wo = kk * 32 + qd * 8;
            kreal = 240; scols = 240; src = Wfc1; dst = Wfc1P; didx = i * 8;
            if (wo < 240) mi = 1;
        } else {                                     // W_fc2 [128][512], no pad
            int i = f - 64384;
            int t = i >> 10, r = i & 1023;
            int kk = r >> 6, qd = (r >> 4) & 3, ln = r & 15;
            row = t * 16 + ln; wo = kk * 32 + qd * 8;
            kreal = 512; scols = 512; src = Wfc2; dst = Wfc2b; didx = i * 8;
            mi = 2;
        }
        ushort4 o0 = {0, 0, 0, 0}, o1 = {0, 0, 0, 0};
        if (wo < kreal) {
            float4 v0 = *(const float4*)(src + (size_t)row * scols + wo);
            float4 v1 = *(const float4*)(src + (size_t)row * scols + wo + 4);
            o0.x = f2bfu(v0.x); o0.y = f2bfu(v0.y); o0.z = f2bfu(v0.z); o0.w = f2bfu(v0.w);
            o1.x = f2bfu(v1.x); o1.y = f2bfu(v1.y); o1.z = f2bfu(v1.z); o1.w = f2bfu(v1.w);
            sq = v0.x * v0.x + v0.y * v0.y + v0.z * v0.z + v0.w * v0.w
               + v1.x * v1.x + v1.y * v1.y + v1.z * v1.z + v1.w * v1.w;
        }
        *(ushort4*)(dst + didx) = o0;
        *(ushort4*)(dst + didx + 4) = o1;
    }
    if (mi >= 0) atomicAdd(&s3[mi], sq);
    __syncthreads();
    if (tid < 3) atomicAdd(&acc[tid], s3[tid]);
}

// x_filt_prev_mean[b][m] = mean_s x_ens[s,b,m]
__global__ void k_colmean(const float* __restrict__ x_ens, float* __restrict__ xfpm) {
    int t = blockIdx.x * 256 + threadIdx.x;   // < 32768
    float s = 0.f;
    for (int ss = 0; ss < 32; ++ss) s += x_ens[ss * 32768 + t];
    xfpm[t] = s * (1.f / 32.f);
}

// per-b: x_pred_mean = xfpm @ F^T, innov = y_t - x_pred_mean @ H^T, feat[48]
__global__ void k_feat(const float* __restrict__ xfpm, const float* __restrict__ F_mat,
                       const float* __restrict__ H_mat, const float* __restrict__ y_t,
                       const float* __restrict__ y_prev, const float* __restrict__ xppm,
                       const float* __restrict__ xpdm, float* __restrict__ feat,
                       float* __restrict__ innov) {
    int b = blockIdx.x * 256 + threadIdx.x;
    if (b >= 2048) return;
    float xm[16];
    #pragma unroll
    for (int m = 0; m < 16; ++m) xm[m] = xfpm[b * 16 + m];
    float xpm[16];
    #pragma unroll
    for (int k = 0; k < 16; ++k) {
        float a = 0.f;
        #pragma unroll
        for (int m = 0; m < 16; ++m) a += xm[m] * F_mat[k * 16 + m];
        xpm[k] = a;
    }
    #pragma unroll
    for (int n = 0; n < 8; ++n) {
        float a = 0.f;
        #pragma unroll
        for (int k = 0; k < 16; ++k) a += xpm[k] * H_mat[n * 16 + k];
        float inn = y_t[b * 8 + n] - a;
        innov[b * 8 + n] = inn;
        feat[b * 48 + 16 + n] = inn;
        feat[b * 48 + 40 + n] = y_t[b * 8 + n] - y_prev[b * 8 + n];
    }
    #pragma unroll
    for (int m = 0; m < 16; ++m) {
        feat[b * 48 + m]      = xm[m] - xpdm[b * 16 + m];
        feat[b * 48 + 24 + m] = xm[m] - xppm[b * 16 + m];
    }
}

// ---------------- fully fused DNN + Kalman-update kernel (32 rows/block, 512 thr) ----------------
// Rd12 lesson: smaller blocks (more occupancy) HURT — per-CU weight-load issue doubled, time
// +48%. Binding constraint = dependent weight-load latency per wave, not wave count.
// This round: Rd9 structure (best measured) + 1-deep register double-buffer of weight
// fragments in P2/P3/P4 — issue kk+1's loads before kk's MFMA chain. Budget: Rd9 used
// 60 VGPR + 24 AGPR of the 128 cap (launch_bounds(512,2) => 2 blocks/CU, LDS-matched);
// prefetch adds ~24-28 VGPR -> ~95-120, still no spill. Numerics bit-identical.
__global__ __launch_bounds__(512, 2) void k_fused(
    const float* __restrict__ feat, const float* __restrict__ u_in_g,
    const float* __restrict__ h_ens, const float* __restrict__ u_fc1_g,
    const float* __restrict__ u_fc2_g,
    const unsigned short* __restrict__ WinP, const unsigned short* __restrict__ WihP,
    const unsigned short* __restrict__ WhhP, const unsigned short* __restrict__ Wfc1P,
    const unsigned short* __restrict__ Wfc2b,
    const float* __restrict__ b_in, const float* __restrict__ b_ih,
    const float* __restrict__ b_hh, const float* __restrict__ b_fc1,
    const float* __restrict__ b_fc2,
    const float* __restrict__ p_in_l, const float* __restrict__ p_fc1_l,
    const float* __restrict__ p_fc2_l,
    const float* __restrict__ innov_ws, const float* __restrict__ x_ens,
    const float* __restrict__ F_mat, float* __restrict__ out) {

    __shared__ __align__(16) char smem[59392];
    unsigned short* sAin = (unsigned short*)smem;
    unsigned short* sA1  = (unsigned short*)(smem + 4608);
    unsigned short* sA2  = (unsigned short*)(smem + 21504);
    unsigned short* sHd  = (unsigned short*)(smem + 38400);
    unsigned short* sA5  = (unsigned short*)smem;
    float* sInn = (float*)(smem + 55296);
    float* sF   = (float*)(smem + 56320);
    float* sOut = (float*)(smem + 57344);

    int tid = threadIdx.x;
    int lane = tid & 63, wave = tid >> 6;
    int blk = blockIdx.x;
    int r0 = blk * 32;            // flattened ensemble row (s*2048 + b)
    int b0 = (blk & 63) * 32;     // batch row (feat/innov index)
    float plog_in = p_in_l[0];  float sc_in = 1.f / (1.f - sigm(plog_in));
    float plog_f1 = p_fc1_l[0]; float sc_f1 = 1.f / (1.f - sigm(plog_f1));
    float plog_f2 = p_fc2_l[0]; float sc_f2 = 1.f / (1.f - sigm(plog_f2));

    // ---- P0: stage A_in (cdrop), h_ens->bf16, innov, F; zero K-pads ----
    if (tid < 384) {
        int row = tid / 12, k = (tid % 12) * 4;
        float4 f = *(const float4*)(feat + (b0 + row) * 48 + k);
        float4 u = *(const float4*)(u_in_g + (size_t)(r0 + row) * 48 + k);
        ushort4 o;
        o.x = f2bfu(cdrop(f.x, u.x, plog_in, sc_in));
        o.y = f2bfu(cdrop(f.y, u.y, plog_in, sc_in));
        o.z = f2bfu(cdrop(f.z, u.z, plog_in, sc_in));
        o.w = f2bfu(cdrop(f.w, u.w, plog_in, sc_in));
        *(ushort4*)(sAin + row * 72 + k) = o;
    }
    if (tid < 128) {   // zero pad A_in k in [48,64)
        int row = tid / 4, k = 48 + (tid % 4) * 4;
        ushort4 z4 = {0, 0, 0, 0};
        *(ushort4*)(sAin + row * 72 + k) = z4;
    }
    for (int c = tid; c < 1920; c += 512) {
        int row = c / 60, k = (c % 60) * 4;
        float4 h = *(const float4*)(h_ens + (size_t)(r0 + row) * 240 + k);
        ushort4 o;
        o.x = f2bfu(h.x); o.y = f2bfu(h.y); o.z = f2bfu(h.z); o.w = f2bfu(h.w);
        *(ushort4*)(sA2 + row * 264 + k) = o;
    }
    if (tid < 192) {   // zero pads k in [240,264) for sA1, sA2, sHd
        int row = tid / 6, k = 240 + (tid % 6) * 4;
        ushort4 z4 = {0, 0, 0, 0};
        *(ushort4*)(sA2 + row * 264 + k) = z4;
        *(ushort4*)(sA1 + row * 264 + k) = z4;
        *(ushort4*)(sHd + row * 264 + k) = z4;
    }
    if (tid < 64) *(float4*)(sInn + tid * 4) = *(const float4*)(innov_ws + b0 * 8 + tid * 4);
    if (tid >= 64 && tid < 128) {
        int q = tid - 64;
        *(float4*)(sF + q * 4) = *(const float4*)(F_mat + q * 4);
    }
    __syncthreads();

    int ln = lane & 15, qd = lane >> 4;

    // ---- P1: x1 = relu(A_in @ W_in^T + b_in) -> sA1 (fragment-ordered WinP) ----
    for (int t = wave; t < 15; t += 8) {
        int col = t * 16 + ln;
        float bias = b_in[col];
        f32x4 a0 = {0.f, 0.f, 0.f, 0.f}, a1v = {0.f, 0.f, 0.f, 0.f};
        #pragma unroll
        for (int kk = 0; kk < 2; ++kk) {
            bf16x8 b = *(const bf16x8*)(WinP + ((t * 2 + kk) * 64 + lane) * 8);
            bf16x8 x0 = *(const bf16x8*)(sAin + ln * 72 + kk * 32 + qd * 8);
            bf16x8 x1 = *(const bf16x8*)(sAin + (16 + ln) * 72 + kk * 32 + qd * 8);
            a0 = MFMA(x0, b, a0);
            a1v = MFMA(x1, b, a1v);
        }
        #pragma unroll
        for (int i = 0; i < 4; ++i) {
            int row = qd * 4 + i;
            float v0 = a0[i] + bias;
            float v1 = a1v[i] + bias;
            sA1[row * 264 + col]        = f2bfu(v0 > 0.f ? v0 : 0.f);
            sA1[(16 + row) * 264 + col] = f2bfu(v1 > 0.f ? v1 : 0.f);
        }
    }
    __syncthreads();

    // ---- P2: GRU over 30 (t,sub) units; 6 acc (24 AGPR); 1-deep weight prefetch ----
    // Gate g base offset in fragment layout: g * 61440 ushorts (15 t x 512 frags x 8).
    for (int u = wave; u < 30; u += 8) {
        int t = u >> 1, sub = u & 1;
        int j = t * 16 + ln;
        float upf[4];
        #pragma unroll
        for (int i = 0; i < 4; ++i) {
            int row = sub * 16 + qd * 4 + i;
            upf[i] = u_fc1_g[(size_t)(r0 + row) * 240 + j];
        }
        float bir_b = b_ih[j], biz_b = b_ih[240 + j], bin_b = b_ih[480 + j];
        float bhr_b = b_hh[j], bhz_b = b_hh[240 + j], bhn_b = b_hh[480 + j];
        f32x4 air = {0,0,0,0}, aiz = {0,0,0,0}, ain = {0,0,0,0};
        f32x4 ahr = {0,0,0,0}, ahz = {0,0,0,0}, ahn = {0,0,0,0};
        int wb0 = (t * 8 * 64 + lane) * 8;
        bf16x8 nir = *(const bf16x8*)(WihP + wb0);
        bf16x8 niz = *(const bf16x8*)(WihP + 61440 + wb0);
        bf16x8 nin = *(const bf16x8*)(WihP + 122880 + wb0);
        bf16x8 nhr = *(const bf16x8*)(WhhP + wb0);
        bf16x8 nhz = *(const bf16x8*)(WhhP + 61440 + wb0);
        bf16x8 nhn = *(const bf16x8*)(WhhP + 122880 + wb0);
        #pragma unroll
        for (int kk = 0; kk < 8; ++kk) {
            bf16x8 cir = nir, ciz = niz, cin_ = nin;
            bf16x8 chr_ = nhr, chz = nhz, chn = nhn;
            if (kk < 7) {   // issue next-kk loads before this kk's MFMA chain
                int wb = ((t * 8 + kk + 1) * 64 + lane) * 8;
                nir = *(const bf16x8*)(WihP + wb);
                niz = *(const bf16x8*)(WihP + 61440 + wb);
                nin = *(const bf16x8*)(WihP + 122880 + wb);
                nhr = *(const bf16x8*)(WhhP + wb);
                nhz = *(const bf16x8*)(WhhP + 61440 + wb);
                nhn = *(const bf16x8*)(WhhP + 122880 + wb);
            }
            int ao = (sub * 16 + ln) * 264 + kk * 32 + qd * 8;
            bf16x8 a1f = *(const bf16x8*)(sA1 + ao);
            bf16x8 a2f = *(const bf16x8*)(sA2 + ao);
            air = MFMA(a1f, cir, air);
            aiz = MFMA(a1f, ciz, aiz);
            ain = MFMA(a1f, cin_, ain);
            ahr = MFMA(a2f, chr_, ahr);
            ahz = MFMA(a2f, chz, ahz);
            ahn = MFMA(a2f, chn, ahn);
        }
        #pragma unroll
        for (int i = 0; i < 4; ++i) {
            int row = sub * 16 + qd * 4 + i;
            float rg = sigm(air[i] + bir_b + ahr[i] + bhr_b);
            float zg = sigm(aiz[i] + biz_b + ahz[i] + bhz_b);
            float ng = tanh_f(ain[i] + bin_b + rg * (ahn[i] + bhn_b));
            float hp = bf2f(sA2[row * 264 + j]);
            float hn2 = (1.f - zg) * ng + zg * hp;
            sHd[row * 264 + j] = f2bfu(cdrop(hn2, upf[i], plog_f1, sc_f1));
        }
    }
    __syncthreads();

    // ---- P3: x2 = relu(hd @ W_fc1^T + b); cdrop(u_fc2) -> sA5; 1-deep prefetch ----
    for (int t = wave; t < 32; t += 8) {
        int col = t * 16 + ln;
        float u0[4], u1[4];
        #pragma unroll
        for (int i = 0; i < 4; ++i) {
            u0[i] = u_fc2_g[(size_t)(r0 + qd * 4 + i) * 512 + col];
            u1[i] = u_fc2_g[(size_t)(r0 + 16 + qd * 4 + i) * 512 + col];
        }
        float bias = b_fc1[col];
        f32x4 a0 = {0.f, 0.f, 0.f, 0.f}, a1v = {0.f, 0.f, 0.f, 0.f};
        bf16x8 nb = *(const bf16x8*)(Wfc1P + ((t * 8) * 64 + lane) * 8);
        #pragma unroll
        for (int kk = 0; kk < 8; ++kk) {
            bf16x8 cb = nb;
            if (kk < 7) nb = *(const bf16x8*)(Wfc1P + ((t * 8 + kk + 1) * 64 + lane) * 8);
            int ao = ln * 264 + kk * 32 + qd * 8;
            bf16x8 x0 = *(const bf16x8*)(sHd + ao);
            bf16x8 x1 = *(const bf16x8*)(sHd + 16 * 264 + ao);
            a0 = MFMA(x0, cb, a0);
            a1v = MFMA(x1, cb, a1v);
        }
        #pragma unroll
        for (int i = 0; i < 4; ++i) {
            int row = qd * 4 + i;
            float v0 = a0[i] + bias; v0 = v0 > 0.f ? v0 : 0.f;
            float v1 = a1v[i] + bias; v1 = v1 > 0.f ? v1 : 0.f;
            sA5[row * 520 + col]        = f2bfu(cdrop(v0, u0[i], plog_f2, sc_f2));
            sA5[(16 + row) * 520 + col] = f2bfu(cdrop(v1, u1[i], plog_f2, sc_f2));
        }
    }
    __syncthreads();

    // ---- P4: K_vec = A5 @ W_fc2^T + b_fc2; K@innov -> sOut; 1-deep prefetch ----
    {
        int t = wave;              // 8 waves == 8 col-tiles
        int j = t * 16 + ln;
        float bias = b_fc2[j];
        int n = lane & 7;
        int m = 2 * t + ((lane >> 3) & 1);
        f32x4 a0 = {0.f, 0.f, 0.f, 0.f}, a1v = {0.f, 0.f, 0.f, 0.f};
        bf16x8 nb = *(const bf16x8*)(Wfc2b + ((t * 16) * 64 + lane) * 8);
        #pragma unroll
        for (int kk = 0; kk < 16; ++kk) {
            bf16x8 cb = nb;
            if (kk < 15) nb = *(const bf16x8*)(Wfc2b + ((t * 16 + kk + 1) * 64 + lane) * 8);
            int ao = ln * 520 + kk * 32 + qd * 8;
            bf16x8 x0 = *(const bf16x8*)(sA5 + ao);
            bf16x8 x1 = *(const bf16x8*)(sA5 + 16 * 520 + ao);
            a0 = MFMA(x0, cb, a0);
            a1v = MFMA(x1, cb, a1v);
        }
        auto epi2 = [&](int sub, f32x4 accv) {
            #pragma unroll
            for (int i = 0; i < 4; ++i) {
                int row = sub * 16 + qd * 4 + i;
                float kv = accv[i] + bias;
                float pr = kv * sInn[row * 8 + n];
                pr += __shfl_xor(pr, 1);
                pr += __shfl_xor(pr, 2);
                pr += __shfl_xor(pr, 4);
                if (n == 0) sOut[row * 16 + m] = pr;
            }
        };
        epi2(0, a0);
        epi2(1, a1v);
    }
    __syncthreads();

    // ---- P5: out = x_ens @ F^T + K@innov, coalesced single write ----
    if (tid < 32) {
        int row = tid;
        float x[16];
        #pragma unroll
        for (int q = 0; q < 4; ++q)
            *(float4*)(x + q * 4) = *(const float4*)(x_ens + (size_t)(r0 + row) * 16 + q * 4);
        #pragma unroll
        for (int mq = 0; mq < 4; ++mq) {
            float4 o;
            float* op = (float*)&o;
            #pragma unroll
            for (int mm = 0; mm < 4; ++mm) {
                int m = mq * 4 + mm;
                float a = 0.f;
                #pragma unroll
                for (int k2 = 0; k2 < 16; ++k2) a += sF[m * 16 + k2] * x[k2];
                op[mm] = a + sOut[row * 16 + m];
            }
            *(float4*)(out + (size_t)(r0 + row) * 16 + mq * 4) = o;
        }
    }
}

// ---------------- regularizer ----------------
__global__ void k_reg(const float* __restrict__ acc, const float* __restrict__ pin,
                      const float* __restrict__ pfc1, const float* __restrict__ pfc2,
                      float* __restrict__ out) {
    float fan[3] = {48.f, 240.f, 512.f};
    float pl[3] = {pin[0], pfc1[0], pfc2[0]};
    float reg = 0.f;
    for (int i = 0; i < 3; ++i) {
        float p = 1.f / (1.f + expf(-pl[i]));
        reg += acc[i] / (1.f - p) + fan[i] * (p * logf(p) + (1.f - p) * logf(1.f - p));
    }
    if (threadIdx.x < 32) out[1048576 + threadIdx.x] = reg;
}

// ---------------- launch ----------------
extern "C" void kernel_launch(void* const* d_in, const int* in_sizes, int n_in,
                              void* d_out, int out_size, void* d_ws, size_t ws_size,
                              hipStream_t stream) {
    const float* y_t    = (const float*)d_in[0];
    const float* x_ens  = (const float*)d_in[1];
    const float* xppm   = (const float*)d_in[2];
    const float* xpdm   = (const float*)d_in[3];
    const float* y_prev = (const float*)d_in[4];
    const float* h_ens  = (const float*)d_in[5];
    const float* F_mat  = (const float*)d_in[6];
    const float* H_mat  = (const float*)d_in[7];
    const float* W_in   = (const float*)d_in[8];
    const float* b_in   = (const float*)d_in[9];
    const float* W_ih   = (const float*)d_in[10];
    const float* b_ih   = (const float*)d_in[11];
    const float* W_hh   = (const float*)d_in[12];
    const float* b_hh   = (const float*)d_in[13];
    const float* W_fc1  = (const float*)d_in[14];
    const float* b_fc1  = (const float*)d_in[15];
    const float* W_fc2  = (const float*)d_in[16];
    const float* b_fc2  = (const float*)d_in[17];
    const float* p_in   = (const float*)d_in[18];
    const float* p_fc1  = (const float*)d_in[19];
    const float* p_fc2  = (const float*)d_in[20];
    const float* u_in   = (const float*)d_in[21];
    const float* u_fc1  = (const float*)d_in[22];
    const float* u_fc2  = (const float*)d_in[23];

    char* ws = (char*)d_ws;
    float* acc            = (float*)(ws + 0);
    unsigned short* WinP  = (unsigned short*)(ws + 64);
    unsigned short* WihP  = (unsigned short*)(ws + 30784);
    unsigned short* WhhP  = (unsigned short*)(ws + 399424);
    unsigned short* Wfc1P = (unsigned short*)(ws + 768064);
    unsigned short* Wfc2b = (unsigned short*)(ws + 1030208);
    float* xfpm           = (float*)(ws + 1161280);
    float* feat           = (float*)(ws + 1292352);
    float* innov          = (float*)(ws + 1685568);
    float* out = (float*)d_out;

    k_zero<<<1, 64, 0, stream>>>(acc);
    k_convert<<<284, 256, 0, stream>>>(W_in, W_ih, W_hh, W_fc1, W_fc2,
                                       WinP, WihP, WhhP, Wfc1P, Wfc2b, acc);
    k_colmean<<<128, 256, 0, stream>>>(x_ens, xfpm);
    k_feat<<<8, 256, 0, stream>>>(xfpm, F_mat, H_mat, y_t, y_prev, xppm, xpdm, feat, innov);
    k_fused<<<2048, 512, 0, stream>>>(feat, u_in, h_ens, u_fc1, u_fc2,
                                      WinP, WihP, WhhP, Wfc1P, Wfc2b,
                                      b_in, b_ih, b_hh, b_fc1, b_fc2,
                                      p_in, p_fc1, p_fc2, innov, x_ens, F_mat, out);
    k_reg<<<1, 64, 0, stream>>>(acc, p_in, p_fc1, p_fc2, out);
}

// Round 14
// 492.868 us; speedup vs baseline: 1.2641x; 1.2070x over previous
//
#include <hip/hip_runtime.h>

// ---------------- types / helpers ----------------
typedef __bf16 bf16x8 __attribute__((ext_vector_type(8)));
typedef float  f32x4  __attribute__((ext_vector_type(4)));

__device__ __forceinline__ f32x4 MFMA(bf16x8 a, bf16x8 b, f32x4 c) {
    return __builtin_amdgcn_mfma_f32_16x16x32_bf16(a, b, c, 0, 0, 0);
}

__device__ __forceinline__ unsigned short f2bfu(float f) {
    unsigned int u = __builtin_bit_cast(unsigned int, f);
    u += 0x7FFFu + ((u >> 16) & 1u);
    return (unsigned short)(u >> 16);
}
__device__ __forceinline__ float bf2f(unsigned short s) {
    unsigned int u = ((unsigned int)s) << 16;
    return __builtin_bit_cast(float, u);
}
__device__ __forceinline__ float sigm(float x) { return 1.f / (1.f + __expf(-x)); }
__device__ __forceinline__ float tanh_f(float x) { return 1.f - 2.f / (__expf(2.f * x) + 1.f); }
// concrete dropout: z = sigmoid((plog + log u - log(1-u))/0.1); out = x*(1-z)/(1-p)
__device__ __forceinline__ float cdrop(float x, float u, float plog, float scale) {
    float t = (plog + __logf(u) - __logf(1.f - u)) * 10.f;
    float z = 1.f / (1.f + __expf(-t));
    return x * (1.f - z) * scale;
}

// ---------------- merged setup kernel: convert (blocks 0..283) + colmean/feat (284..291) ----
// Convert: fp32 -> bf16 in MFMA-FRAGMENT order; per-block sum(W*W) partials -> part[i][blk]
// (replaces k_zero + global atomics). frag[t][kk][lane][8]: lane = qd*16+ln holds
// W[t*16+ln][kk*32+qd*8 .. +7]; a wave's B-fragment load is ONE contiguous 1 KB global_load.
// Colfeat: per-thread column-mean of x_ens (same ss-ascending order as old k_colmean,
// bit-identical), then the k_feat math verbatim -> feat, innov.
__global__ void k_setup(const float* __restrict__ Win, const float* __restrict__ Wih,
                        const float* __restrict__ Whh, const float* __restrict__ Wfc1,
                        const float* __restrict__ Wfc2,
                        unsigned short* __restrict__ WinP, unsigned short* __restrict__ WihP,
                        unsigned short* __restrict__ WhhP, unsigned short* __restrict__ Wfc1P,
                        unsigned short* __restrict__ Wfc2b, float* __restrict__ part,
                        const float* __restrict__ x_ens, const float* __restrict__ F_mat,
                        const float* __restrict__ H_mat, const float* __restrict__ y_t,
                        const float* __restrict__ y_prev, const float* __restrict__ xppm,
                        const float* __restrict__ xpdm, float* __restrict__ feat,
                        float* __restrict__ innov) {
    __shared__ float s3[3];
    int tid = threadIdx.x;
    int blk = blockIdx.x;
    if (blk < 284) {
        // ---------------- convert ----------------
        if (tid < 3) s3[tid] = 0.f;
        __syncthreads();
        int f = blk * 256 + tid;   // fragment id, total 72576
        float sq = 0.f; int mi = -1;
        if (f < 72576) {
            const float* src; unsigned short* dst;
            int row, wo, kreal, scols, didx;
            if (f < 1920) {                              // W_in [240][48->64], 128 frags/t
                int t = f >> 7, r = f & 127;
                int kk = r >> 6, qd = (r >> 4) & 3, ln = r & 15;
                row = t * 16 + ln; wo = kk * 32 + qd * 8;
                kreal = 48; scols = 48; src = Win; dst = WinP; didx = f * 8;
                if (wo < 48) mi = 0;
            } else if (f < 24960) {                      // W_ih [720][240->256], 512 frags/t'
                int i = f - 1920;
                int tp = i >> 9, r = i & 511;
                int kk = r >> 6, qd = (r >> 4) & 3, ln = r & 15;
                row = (tp / 15) * 240 + (tp % 15) * 16 + ln; wo = kk * 32 + qd * 8;
                kreal = 240; scols = 240; src = Wih; dst = WihP; didx = i * 8;
            } else if (f < 48000) {                      // W_hh
                int i = f - 24960;
                int tp = i >> 9, r = i & 511;
                int kk = r >> 6, qd = (r >> 4) & 3, ln = r & 15;
                row = (tp / 15) * 240 + (tp % 15) * 16 + ln; wo = kk * 32 + qd * 8;
                kreal = 240; scols = 240; src = Whh; dst = WhhP; didx = i * 8;
            } else if (f < 64384) {                      // W_fc1 [512][240->256]
                int i = f - 48000;
                int t = i >> 9, r = i & 511;
                int kk = r >> 6, qd = (r >> 4) & 3, ln = r & 15;
                row = t * 16 + ln; wo = kk * 32 + qd * 8;
                kreal = 240; scols = 240; src = Wfc1; dst = Wfc1P; didx = i * 8;
                if (wo < 240) mi = 1;
            } else {                                     // W_fc2 [128][512], no pad
                int i = f - 64384;
                int t = i >> 10, r = i & 1023;
                int kk = r >> 6, qd = (r >> 4) & 3, ln = r & 15;
                row = t * 16 + ln; wo = kk * 32 + qd * 8;
                kreal = 512; scols = 512; src = Wfc2; dst = Wfc2b; didx = i * 8;
                mi = 2;
            }
            ushort4 o0 = {0, 0, 0, 0}, o1 = {0, 0, 0, 0};
            if (wo < kreal) {
                float4 v0 = *(const float4*)(src + (size_t)row * scols + wo);
                float4 v1 = *(const float4*)(src + (size_t)row * scols + wo + 4);
                o0.x = f2bfu(v0.x); o0.y = f2bfu(v0.y); o0.z = f2bfu(v0.z); o0.w = f2bfu(v0.w);
                o1.x = f2bfu(v1.x); o1.y = f2bfu(v1.y); o1.z = f2bfu(v1.z); o1.w = f2bfu(v1.w);
                sq = v0.x * v0.x + v0.y * v0.y + v0.z * v0.z + v0.w * v0.w
                   + v1.x * v1.x + v1.y * v1.y + v1.z * v1.z + v1.w * v1.w;
            }
            *(ushort4*)(dst + didx) = o0;
            *(ushort4*)(dst + didx + 4) = o1;
        }
        if (mi >= 0) atomicAdd(&s3[mi], sq);
        __syncthreads();
        if (tid < 3) part[tid * 284 + blk] = s3[tid];
    } else {
        // ---------------- colmean + feat ----------------
        int b = (blk - 284) * 256 + tid;   // [0,2048)
        float4 a0 = {0.f, 0.f, 0.f, 0.f}, a1 = a0, a2 = a0, a3 = a0;
        for (int ss = 0; ss < 32; ++ss) {
            const float* p = x_ens + (size_t)ss * 32768 + b * 16;
            float4 v0 = *(const float4*)(p + 0);
            float4 v1 = *(const float4*)(p + 4);
            float4 v2 = *(const float4*)(p + 8);
            float4 v3 = *(const float4*)(p + 12);
            a0.x += v0.x; a0.y += v0.y; a0.z += v0.z; a0.w += v0.w;
            a1.x += v1.x; a1.y += v1.y; a1.z += v1.z; a1.w += v1.w;
            a2.x += v2.x; a2.y += v2.y; a2.z += v2.z; a2.w += v2.w;
            a3.x += v3.x; a3.y += v3.y; a3.z += v3.z; a3.w += v3.w;
        }
        float xm[16];
        *(float4*)(xm + 0)  = a0; *(float4*)(xm + 4)  = a1;
        *(float4*)(xm + 8)  = a2; *(float4*)(xm + 12) = a3;
        #pragma unroll
        for (int m = 0; m < 16; ++m) xm[m] *= (1.f / 32.f);
        float xpm[16];
        #pragma unroll
        for (int k = 0; k < 16; ++k) {
            float a = 0.f;
            #pragma unroll
            for (int m = 0; m < 16; ++m) a += xm[m] * F_mat[k * 16 + m];
            xpm[k] = a;
        }
        #pragma unroll
        for (int n = 0; n < 8; ++n) {
            float a = 0.f;
            #pragma unroll
            for (int k = 0; k < 16; ++k) a += xpm[k] * H_mat[n * 16 + k];
            float inn = y_t[b * 8 + n] - a;
            innov[b * 8 + n] = inn;
            feat[b * 48 + 16 + n] = inn;
            feat[b * 48 + 40 + n] = y_t[b * 8 + n] - y_prev[b * 8 + n];
        }
        #pragma unroll
        for (int m = 0; m < 16; ++m) {
            feat[b * 48 + m]      = xm[m] - xpdm[b * 16 + m];
            feat[b * 48 + 24 + m] = xm[m] - xppm[b * 16 + m];
        }
    }
}

// ---------------- fully fused DNN + Kalman-update kernel (32 rows/block, 512 thr) ----------------
// EXACT Rd9 structure (best measured: 265 us k_fused, 491 total): fragment-ordered weights,
// P2 = 30 (t,sub) units with 6 accumulators (24 AGPR; 60 VGPR + 24 = 84 <= 128 -> 2 blocks/CU).
// Rd13 lesson: any +28-reg addition (prefetch dbuf) crosses the 128 VGPR+AGPR wall -> 1 blk.
// Added (cold path): block 0 / wave 0 sums the 284 convert partials and writes raw_reg,
// replacing k_reg. Launches: 6 -> 2.
__global__ __launch_bounds__(512, 2) void k_fused(
    const float* __restrict__ feat, const float* __restrict__ u_in_g,
    const float* __restrict__ h_ens, const float* __restrict__ u_fc1_g,
    const float* __restrict__ u_fc2_g,
    const unsigned short* __restrict__ WinP, const unsigned short* __restrict__ WihP,
    const unsigned short* __restrict__ WhhP, const unsigned short* __restrict__ Wfc1P,
    const unsigned short* __restrict__ Wfc2b,
    const float* __restrict__ b_in, const float* __restrict__ b_ih,
    const float* __restrict__ b_hh, const float* __restrict__ b_fc1,
    const float* __restrict__ b_fc2,
    const float* __restrict__ p_in_l, const float* __restrict__ p_fc1_l,
    const float* __restrict__ p_fc2_l,
    const float* __restrict__ innov_ws, const float* __restrict__ x_ens,
    const float* __restrict__ F_mat, const float* __restrict__ part,
    float* __restrict__ out) {

    __shared__ __align__(16) char smem[59392];
    unsigned short* sAin = (unsigned short*)smem;
    unsigned short* sA1  = (unsigned short*)(smem + 4608);
    unsigned short* sA2  = (unsigned short*)(smem + 21504);
    unsigned short* sHd  = (unsigned short*)(smem + 38400);
    unsigned short* sA5  = (unsigned short*)smem;
    float* sInn = (float*)(smem + 55296);
    float* sF   = (float*)(smem + 56320);
    float* sOut = (float*)(smem + 57344);

    int tid = threadIdx.x;
    int lane = tid & 63, wave = tid >> 6;
    int blk = blockIdx.x;
    int r0 = blk * 32;            // flattened ensemble row (s*2048 + b)
    int b0 = (blk & 63) * 32;     // batch row (feat/innov index)
    float plog_in = p_in_l[0];  float sc_in = 1.f / (1.f - sigm(plog_in));
    float plog_f1 = p_fc1_l[0]; float sc_f1 = 1.f / (1.f - sigm(plog_f1));
    float plog_f2 = p_fc2_l[0]; float sc_f2 = 1.f / (1.f - sigm(plog_f2));

    // ---- raw_reg (replaces k_reg): block 0, wave 0 only; cold, runs once ----
    if (blk == 0 && wave == 0) {
        float s[3];
        #pragma unroll
        for (int i = 0; i < 3; ++i) {
            float a = 0.f;
            for (int l = lane; l < 284; l += 64) a += part[i * 284 + l];
            #pragma unroll
            for (int off = 32; off; off >>= 1) a += __shfl_xor(a, off);
            s[i] = a;
        }
        float fan[3] = {48.f, 240.f, 512.f};
        float pl[3] = {plog_in, plog_f1, plog_f2};
        float reg = 0.f;
        #pragma unroll
        for (int i = 0; i < 3; ++i) {
            float p = 1.f / (1.f + __expf(-pl[i]));
            reg += s[i] / (1.f - p) + fan[i] * (p * __logf(p) + (1.f - p) * __logf(1.f - p));
        }
        if (lane < 32) out[1048576 + lane] = reg;
    }

    // ---- P0: stage A_in (cdrop), h_ens->bf16, innov, F; zero K-pads ----
    if (tid < 384) {
        int row = tid / 12, k = (tid % 12) * 4;
        float4 f = *(const float4*)(feat + (b0 + row) * 48 + k);
        float4 u = *(const float4*)(u_in_g + (size_t)(r0 + row) * 48 + k);
        ushort4 o;
        o.x = f2bfu(cdrop(f.x, u.x, plog_in, sc_in));
        o.y = f2bfu(cdrop(f.y, u.y, plog_in, sc_in));
        o.z = f2bfu(cdrop(f.z, u.z, plog_in, sc_in));
        o.w = f2bfu(cdrop(f.w, u.w, plog_in, sc_in));
        *(ushort4*)(sAin + row * 72 + k) = o;
    }
    if (tid < 128) {   // zero pad A_in k in [48,64)
        int row = tid / 4, k = 48 + (tid % 4) * 4;
        ushort4 z4 = {0, 0, 0, 0};
        *(ushort4*)(sAin + row * 72 + k) = z4;
    }
    for (int c = tid; c < 1920; c += 512) {
        int row = c / 60, k = (c % 60) * 4;
        float4 h = *(const float4*)(h_ens + (size_t)(r0 + row) * 240 + k);
        ushort4 o;
        o.x = f2bfu(h.x); o.y = f2bfu(h.y); o.z = f2bfu(h.z); o.w = f2bfu(h.w);
        *(ushort4*)(sA2 + row * 264 + k) = o;
    }
    if (tid < 192) {   // zero pads k in [240,264) for sA1, sA2, sHd
        int row = tid / 6, k = 240 + (tid % 6) * 4;
        ushort4 z4 = {0, 0, 0, 0};
        *(ushort4*)(sA2 + row * 264 + k) = z4;
        *(ushort4*)(sA1 + row * 264 + k) = z4;
        *(ushort4*)(sHd + row * 264 + k) = z4;
    }
    if (tid < 64) *(float4*)(sInn + tid * 4) = *(const float4*)(innov_ws + b0 * 8 + tid * 4);
    if (tid >= 64 && tid < 128) {
        int q = tid - 64;
        *(float4*)(sF + q * 4) = *(const float4*)(F_mat + q * 4);
    }
    __syncthreads();

    int ln = lane & 15, qd = lane >> 4;

    // ---- P1: x1 = relu(A_in @ W_in^T + b_in) -> sA1 (fragment-ordered WinP) ----
    for (int t = wave; t < 15; t += 8) {
        int col = t * 16 + ln;
        float bias = b_in[col];
        f32x4 a0 = {0.f, 0.f, 0.f, 0.f}, a1v = {0.f, 0.f, 0.f, 0.f};
        #pragma unroll
        for (int kk = 0; kk < 2; ++kk) {
            bf16x8 b = *(const bf16x8*)(WinP + ((t * 2 + kk) * 64 + lane) * 8);
            bf16x8 x0 = *(const bf16x8*)(sAin + ln * 72 + kk * 32 + qd * 8);
            bf16x8 x1 = *(const bf16x8*)(sAin + (16 + ln) * 72 + kk * 32 + qd * 8);
            a0 = MFMA(x0, b, a0);
            a1v = MFMA(x1, b, a1v);
        }
        #pragma unroll
        for (int i = 0; i < 4; ++i) {
            int row = qd * 4 + i;
            float v0 = a0[i] + bias;
            float v1 = a1v[i] + bias;
            sA1[row * 264 + col]        = f2bfu(v0 > 0.f ? v0 : 0.f);
            sA1[(16 + row) * 264 + col] = f2bfu(v1 > 0.f ? v1 : 0.f);
        }
    }
    __syncthreads();

    // ---- P2: GRU over 30 (t,sub) units; 6 accumulators (24 AGPR) ----
    // Gate g base offset in fragment layout: g * 61440 ushorts (15 t x 512 frags x 8).
    for (int u = wave; u < 30; u += 8) {
        int t = u >> 1, sub = u & 1;
        int j = t * 16 + ln;
        float upf[4];
        #pragma unroll
        for (int i = 0; i < 4; ++i) {
            int row = sub * 16 + qd * 4 + i;
            upf[i] = u_fc1_g[(size_t)(r0 + row) * 240 + j];
        }
        float bir_b = b_ih[j], biz_b = b_ih[240 + j], bin_b = b_ih[480 + j];
        float bhr_b = b_hh[j], bhz_b = b_hh[240 + j], bhn_b = b_hh[480 + j];
        f32x4 air = {0,0,0,0}, aiz = {0,0,0,0}, ain = {0,0,0,0};
        f32x4 ahr = {0,0,0,0}, ahz = {0,0,0,0}, ahn = {0,0,0,0};
        #pragma unroll
        for (int kk = 0; kk < 8; ++kk) {
            int wb = ((t * 8 + kk) * 64 + lane) * 8;
            bf16x8 bir = *(const bf16x8*)(WihP + wb);
            bf16x8 biz = *(const bf16x8*)(WihP + 61440 + wb);
            bf16x8 bin_ = *(const bf16x8*)(WihP + 122880 + wb);
            bf16x8 bhr = *(const bf16x8*)(WhhP + wb);
            bf16x8 bhz = *(const bf16x8*)(WhhP + 61440 + wb);
            bf16x8 bhn = *(const bf16x8*)(WhhP + 122880 + wb);
            int ao = (sub * 16 + ln) * 264 + kk * 32 + qd * 8;
            bf16x8 a1f = *(const bf16x8*)(sA1 + ao);
            bf16x8 a2f = *(const bf16x8*)(sA2 + ao);
            air = MFMA(a1f, bir, air);
            aiz = MFMA(a1f, biz, aiz);
            ain = MFMA(a1f, bin_, ain);
            ahr = MFMA(a2f, bhr, ahr);
            ahz = MFMA(a2f, bhz, ahz);
            ahn = MFMA(a2f, bhn, ahn);
        }
        #pragma unroll
        for (int i = 0; i < 4; ++i) {
            int row = sub * 16 + qd * 4 + i;
            float rg = sigm(air[i] + bir_b + ahr[i] + bhr_b);
            float zg = sigm(aiz[i] + biz_b + ahz[i] + bhz_b);
            float ng = tanh_f(ain[i] + bin_b + rg * (ahn[i] + bhn_b));
            float hp = bf2f(sA2[row * 264 + j]);
            float hn2 = (1.f - zg) * ng + zg * hp;
            sHd[row * 264 + j] = f2bfu(cdrop(hn2, upf[i], plog_f1, sc_f1));
        }
    }
    __syncthreads();

    // ---- P3: x2 = relu(hd @ W_fc1^T + b); cdrop(u_fc2) -> sA5 (aliases dead bufs) ----
    for (int t = wave; t < 32; t += 8) {
        int col = t * 16 + ln;
        float u0[4], u1[4];
        #pragma unroll
        for (int i = 0; i < 4; ++i) {
            u0[i] = u_fc2_g[(size_t)(r0 + qd * 4 + i) * 512 + col];
            u1[i] = u_fc2_g[(size_t)(r0 + 16 + qd * 4 + i) * 512 + col];
        }
        float bias = b_fc1[col];
        f32x4 a0 = {0.f, 0.f, 0.f, 0.f}, a1v = {0.f, 0.f, 0.f, 0.f};
        #pragma unroll
        for (int kk = 0; kk < 8; ++kk) {
            bf16x8 b = *(const bf16x8*)(Wfc1P + ((t * 8 + kk) * 64 + lane) * 8);
            int ao = ln * 264 + kk * 32 + qd * 8;
            bf16x8 x0 = *(const bf16x8*)(sHd + ao);
            bf16x8 x1 = *(const bf16x8*)(sHd + 16 * 264 + ao);
            a0 = MFMA(x0, b, a0);
            a1v = MFMA(x1, b, a1v);
        }
        #pragma unroll
        for (int i = 0; i < 4; ++i) {
            int row = qd * 4 + i;
            float v0 = a0[i] + bias; v0 = v0 > 0.f ? v0 : 0.f;
            float v1 = a1v[i] + bias; v1 = v1 > 0.f ? v1 : 0.f;
            sA5[row * 520 + col]        = f2bfu(cdrop(v0, u0[i], plog_f2, sc_f2));
            sA5[(16 + row) * 520 + col] = f2bfu(cdrop(v1, u1[i], plog_f2, sc_f2));
        }
    }
    __syncthreads();

    // ---- P4: K_vec = A5 @ W_fc2^T + b_fc2; K@innov -> sOut ----
    {
        int t = wave;              // 8 waves == 8 col-tiles
        int j = t * 16 + ln;
        float bias = b_fc2[j];
        int n = lane & 7;
        int m = 2 * t + ((lane >> 3) & 1);
        f32x4 a0 = {0.f, 0.f, 0.f, 0.f}, a1v = {0.f, 0.f, 0.f, 0.f};
        #pragma unroll
        for (int kk = 0; kk < 16; ++kk) {
            bf16x8 b = *(const bf16x8*)(Wfc2b + ((t * 16 + kk) * 64 + lane) * 8);
            int ao = ln * 520 + kk * 32 + qd * 8;
            bf16x8 x0 = *(const bf16x8*)(sA5 + ao);
            bf16x8 x1 = *(const bf16x8*)(sA5 + 16 * 520 + ao);
            a0 = MFMA(x0, b, a0);
            a1v = MFMA(x1, b, a1v);
        }
        auto epi2 = [&](int sub, f32x4 accv) {
            #pragma unroll
            for (int i = 0; i < 4; ++i) {
                int row = sub * 16 + qd * 4 + i;
                float kv = accv[i] + bias;
                float pr = kv * sInn[row * 8 + n];
                pr += __shfl_xor(pr, 1);
                pr += __shfl_xor(pr, 2);
                pr += __shfl_xor(pr, 4);
                if (n == 0) sOut[row * 16 + m] = pr;
            }
        };
        epi2(0, a0);
        epi2(1, a1v);
    }
    __syncthreads();

    // ---- P5: out = x_ens @ F^T + K@innov, coalesced single write ----
    if (tid < 32) {
        int row = tid;
        float x[16];
        #pragma unroll
        for (int q = 0; q < 4; ++q)
            *(float4*)(x + q * 4) = *(const float4*)(x_ens + (size_t)(r0 + row) * 16 + q * 4);
        #pragma unroll
        for (int mq = 0; mq < 4; ++mq) {
            float4 o;
            float* op = (float*)&o;
            #pragma unroll
            for (int mm = 0; mm < 4; ++mm) {
                int m = mq * 4 + mm;
                float a = 0.f;
                #pragma unroll
                for (int k2 = 0; k2 < 16; ++k2) a += sF[m * 16 + k2] * x[k2];
                op[mm] = a + sOut[row * 16 + m];
            }
            *(float4*)(out + (size_t)(r0 + row) * 16 + mq * 4) = o;
        }
    }
}

// ---------------- launch ----------------
extern "C" void kernel_launch(void* const* d_in, const int* in_sizes, int n_in,
                              void* d_out, int out_size, void* d_ws, size_t ws_size,
                              hipStream_t stream) {
    const float* y_t    = (const float*)d_in[0];
    const float* x_ens  = (const float*)d_in[1];
    const float* xppm   = (const float*)d_in[2];
    const float* xpdm   = (const float*)d_in[3];
    const float* y_prev = (const float*)d_in[4];
    const float* h_ens  = (const float*)d_in[5];
    const float* F_mat  = (const float*)d_in[6];
    const float* H_mat  = (const float*)d_in[7];
    const float* W_in   = (const float*)d_in[8];
    const float* b_in   = (const float*)d_in[9];
    const float* W_ih   = (const float*)d_in[10];
    const float* b_ih   = (const float*)d_in[11];
    const float* W_hh   = (const float*)d_in[12];
    const float* b_hh   = (const float*)d_in[13];
    const float* W_fc1  = (const float*)d_in[14];
    const float* b_fc1  = (const float*)d_in[15];
    const float* W_fc2  = (const float*)d_in[16];
    const float* b_fc2  = (const float*)d_in[17];
    const float* p_in   = (const float*)d_in[18];
    const float* p_fc1  = (const float*)d_in[19];
    const float* p_fc2  = (const float*)d_in[20];
    const float* u_in   = (const float*)d_in[21];
    const float* u_fc1  = (const float*)d_in[22];
    const float* u_fc2  = (const float*)d_in[23];

    char* ws = (char*)d_ws;
    unsigned short* WinP  = (unsigned short*)(ws + 64);
    unsigned short* WihP  = (unsigned short*)(ws + 30784);
    unsigned short* WhhP  = (unsigned short*)(ws + 399424);
    unsigned short* Wfc1P = (unsigned short*)(ws + 768064);
    unsigned short* Wfc2b = (unsigned short*)(ws + 1030208);
    float* feat           = (float*)(ws + 1292352);
    float* innov          = (float*)(ws + 1685568);
    float* part           = (float*)(ws + 1751104);   // [3][284] convert partials
    float* out = (float*)d_out;

    k_setup<<<292, 256, 0, stream>>>(W_in, W_ih, W_hh, W_fc1, W_fc2,
                                     WinP, WihP, WhhP, Wfc1P, Wfc2b, part,
                                     x_ens, F_mat, H_mat, y_t, y_prev, xppm, xpdm,
                                     feat, innov);
    k_fused<<<2048, 512, 0, stream>>>(feat, u_in, h_ens, u_fc1, u_fc2,
                                      WinP, WihP, WhhP, Wfc1P, Wfc2b,
                                      b_in, b_ih, b_hh, b_fc1, b_fc2,
                                      p_in, p_fc1, p_fc2, innov, x_ens, F_mat, part, out);
}